// Round 3
// baseline (484.869 us; speedup 1.0000x reference)
//
#include <hip/hip_runtime.h>
#include <hip/hip_fp16.h>

// GCN: 4 layers, N=50000, E=800000, C: 128->96->96->96->96
// - 8-way XCD-partitioned CSR counting sort (part = (edge>>8)&7 == blockIdx%8
//   heuristic -> XCD-private scatter regions, kills write ping-pong)
// - MFMA f16 GEMM, no LDS in main loop: A read from swizzled-fp16 global
//   (written by agg), W pre-swizzled fp16; D^T trick for packed row-major
//   fp16 stores. Layer 1 stages fp32 x -> swizzled fp16 LDS.
// - agg: fp16 gathers, fp32 accumulate, writes swizzled fp16 for next GEMM.

#define NN 50000
#define NE 800000
#define K1 128
#define CH 96
#define NT 3125   // NN/16 row-tiles (exact)
#define NPART 8

typedef _Float16 v8h __attribute__((ext_vector_type(8)));
typedef _Float16 v4h __attribute__((ext_vector_type(4)));
typedef float f4 __attribute__((ext_vector_type(4)));

static inline size_t al256(size_t x) { return (x + 255) & ~size_t(255); }

// ---------------- graph preprocessing ----------------

__global__ void count_deg_k(const int* __restrict__ dst, int* __restrict__ cnt8, int e) {
    int i = blockIdx.x * 256 + threadIdx.x;
    if (i < e) {
        int p = (i >> 8) & 7;  // == blockIdx.x & 7 (256-thread blocks)
        atomicAdd(&cnt8[p * NN + dst[i]], 1);
    }
}

// level-1 scan: 1024 elems/block (4/thread). m % 4 == 0 assumed.
__global__ void scan1v_k(const int* __restrict__ in, int* __restrict__ out,
                         int* __restrict__ bsum, int m) {
    __shared__ int s[256];
    int tid = threadIdx.x;
    int base = blockIdx.x * 1024 + tid * 4;
    int4 v = {0, 0, 0, 0};
    if (base < m) v = *(const int4*)&in[base];
    int t4 = v.x + v.y + v.z + v.w;
    s[tid] = t4;
    __syncthreads();
    for (int d = 1; d < 256; d <<= 1) {
        int t = (tid >= d) ? s[tid - d] : 0;
        __syncthreads();
        s[tid] += t;
        __syncthreads();
    }
    int ex = s[tid] - t4;
    if (base < m) {
        int4 o;
        o.x = ex; o.y = ex + v.x; o.z = o.y + v.y; o.w = o.z + v.z;
        *(int4*)&out[base] = o;
    }
    if (tid == 255) bsum[blockIdx.x] = s[255];
}

// level-2 scan: single block, up to 1024 block sums
__global__ void scan2v_k(const int* __restrict__ bsum, int* __restrict__ boff, int nb) {
    __shared__ int s[256];
    int tid = threadIdx.x;
    int base = tid * 4;
    int v[4];
    int t4 = 0;
#pragma unroll
    for (int j = 0; j < 4; j++) {
        v[j] = (base + j < nb) ? bsum[base + j] : 0;
        t4 += v[j];
    }
    s[tid] = t4;
    __syncthreads();
    for (int d = 1; d < 256; d <<= 1) {
        int t = (tid >= d) ? s[tid - d] : 0;
        __syncthreads();
        s[tid] += t;
        __syncthreads();
    }
    int ex = s[tid] - t4;
#pragma unroll
    for (int j = 0; j < 4; j++) {
        if (base + j < nb) { boff[base + j] = ex; ex += v[j]; }
    }
}

// add block offsets; duplicate into cursor
__global__ void scan3v_k(int* __restrict__ offs, const int* __restrict__ boff,
                         int* __restrict__ cursor, int m) {
    int i = blockIdx.x * 1024 + threadIdx.x * 4;
    if (i < m) {
        int bo = boff[blockIdx.x];
        int4 v = *(int4*)&offs[i];
        v.x += bo; v.y += bo; v.z += bo; v.w += bo;
        *(int4*)&offs[i] = v;
        *(int4*)&cursor[i] = v;
    }
}

// dinv = rsqrt(1 + total degree); also finalize offs8 end sentinel
__global__ void dinv_k(const int* __restrict__ cnt8, float* __restrict__ dinv,
                       int* __restrict__ offs8) {
    int n = blockIdx.x * 256 + threadIdx.x;
    if (n == 0) offs8[NPART * NN] = NE;
    if (n < NN) {
        int d = 0;
#pragma unroll
        for (int p = 0; p < NPART; p++) d += cnt8[p * NN + n];
        dinv[n] = rsqrtf(1.0f + (float)d);
    }
}

__global__ void scatter_k(const int* __restrict__ src, const int* __restrict__ dst,
                          int* __restrict__ cursor, int* __restrict__ es, int e) {
    int i = blockIdx.x * 256 + threadIdx.x;
    if (i < e) {
        int p = (i >> 8) & 7;
        int pos = atomicAdd(&cursor[p * NN + dst[i]], 1);
        es[pos] = src[i];
    }
}

// W[K][96] fp32 row-major -> swizzled fp16 B-operand layout
__global__ void wconv_k(const float* __restrict__ W, _Float16* __restrict__ Wsw, int K) {
    int id = blockIdx.x * 256 + threadIdx.x;
    int kc = K / 4;
    int n = id / kc, k4 = id % kc;
    if (n < 96) {
        int k0 = k4 * 4;
        v4h o;
        o.x = (_Float16)W[(k0 + 0) * 96 + n];
        o.y = (_Float16)W[(k0 + 1) * 96 + n];
        o.z = (_Float16)W[(k0 + 2) * 96 + n];
        o.w = (_Float16)W[(k0 + 3) * 96 + n];
        int off = (n >> 4) * (16 * K) + (k0 >> 3) * 128 + (n & 15) * 8 + (k0 & 7);
        *(v4h*)&Wsw[off] = o;
    }
}

// ---------------- MFMA GEMM: Hh[NN x 96](fp16 row-major) = A @ W ----------------
// block = 128 threads (2 waves); wave computes 64 rows (4 row-tiles) x 96 cols.
// STAGE=true: A = Xf fp32 [NN x K] staged to swizzled fp16 LDS (layer 1).
// STAGE=false: A = Asw swizzled fp16 global (written by agg).
// mfma(b_frag, a_frag, acc) computes D^T: lane holds x-row = lane&15 (in tile),
// w-cols = quad*4 + reg -> 4 consecutive cols -> packed 8B row-major store.
template <int K, bool STAGE>
__global__ __launch_bounds__(128) void gemm_k(const float* __restrict__ Xf,
                                              const _Float16* __restrict__ Asw,
                                              const _Float16* __restrict__ Wsw,
                                              _Float16* __restrict__ Hh) {
    constexpr int KK = K / 32;
    constexpr int LDSN = STAGE ? 128 * K : 8;
    __shared__ _Float16 lds[LDSN];

    int tid = threadIdx.x;
    int wave = tid >> 6;
    int lane = tid & 63;
    int l15 = lane & 15, quad = lane >> 4;
    int bt0 = blockIdx.x * 8;
    int wt0 = bt0 + wave * 4;

    if (STAGE) {
        int row0 = bt0 * 16;
        for (int i = tid; i < 128 * (K / 4); i += 128) {
            int r = i / (K / 4), c = i % (K / 4);
            int gr = row0 + r;
            float4 v = make_float4(0.f, 0.f, 0.f, 0.f);
            if (gr < NN) v = *(const float4*)&Xf[(size_t)gr * K + c * 4];
            int k0 = c * 4;
            v4h h;
            h.x = (_Float16)v.x; h.y = (_Float16)v.y;
            h.z = (_Float16)v.z; h.w = (_Float16)v.w;
            int off = (r >> 4) * (16 * K) + (k0 >> 3) * 128 + (r & 15) * 8 + (k0 & 7);
            *(v4h*)&lds[off] = h;
        }
        __syncthreads();
    }

    f4 acc[4][6];
#pragma unroll
    for (int rt = 0; rt < 4; rt++)
#pragma unroll
        for (int cb = 0; cb < 6; cb++) acc[rt][cb] = {0.f, 0.f, 0.f, 0.f};

    for (int kk = 0; kk < KK; kk++) {
        v8h b[6];
#pragma unroll
        for (int cb = 0; cb < 6; cb++)
            b[cb] = ((const v8h*)Wsw)[cb * (2 * K) + (kk * 4 + quad) * 16 + l15];
        v8h a[4];
#pragma unroll
        for (int rt = 0; rt < 4; rt++) {
            if (STAGE) {
                int off = (wave * 4 + rt) * (16 * K) + (kk * 4 + quad) * 128 + l15 * 8;
                a[rt] = *(v8h*)&lds[off];
            } else {
                int t = wt0 + rt;
                if (t > NT - 1) t = NT - 1;
                a[rt] = ((const v8h*)Asw)[t * 192 + (kk * 4 + quad) * 16 + l15];
            }
        }
#pragma unroll
        for (int rt = 0; rt < 4; rt++)
#pragma unroll
            for (int cb = 0; cb < 6; cb++)
                acc[rt][cb] = __builtin_amdgcn_mfma_f32_16x16x32_f16(b[cb], a[rt], acc[rt][cb], 0, 0, 0);
    }

#pragma unroll
    for (int rt = 0; rt < 4; rt++) {
        int t = wt0 + rt;
        if (t < NT) {
            int row = t * 16 + l15;
#pragma unroll
            for (int cb = 0; cb < 6; cb++) {
                v4h o;
                o.x = (_Float16)acc[rt][cb].x;
                o.y = (_Float16)acc[rt][cb].y;
                o.z = (_Float16)acc[rt][cb].z;
                o.w = (_Float16)acc[rt][cb].w;
                *(v4h*)&Hh[(size_t)row * 96 + cb * 16 + quad * 4] = o;
            }
        }
    }
}

// ---------------- aggregation ----------------
// OUT[n] = sum_{p, e in seg(p,n)} dinv[src]*dinv[n]*Hh[src] + dinv[n]^2*Hh[n] + b
// 24 threads/node (4 halves each), block 192 = 8 nodes.
// mode 0: relu + swizzled fp16 -> Fsw ; mode 1: fp32 row-major -> out
__global__ __launch_bounds__(192) void agg_k(const _Float16* __restrict__ Hh,
                                             const int* __restrict__ offs8,
                                             const int* __restrict__ es,
                                             const float* __restrict__ dinv,
                                             const float* __restrict__ b,
                                             _Float16* __restrict__ Fsw,
                                             float* __restrict__ out, int mode) {
    int tid = threadIdx.x;
    int g = tid / 24, c4 = tid % 24;
    int n = blockIdx.x * 8 + g;
    if (n >= NN) return;
    float di = dinv[n];
    float ax = 0.f, ay = 0.f, az = 0.f, aw = 0.f;
#pragma unroll
    for (int p = 0; p < NPART; p++) {
        int e0 = offs8[p * NN + n], e1 = offs8[p * NN + n + 1];
        for (int e = e0; e < e1; e++) {
            int s = es[e];
            float w = dinv[s] * di;
            v4h h = *(const v4h*)&Hh[(size_t)s * 96 + c4 * 4];
            ax = fmaf(w, (float)h.x, ax);
            ay = fmaf(w, (float)h.y, ay);
            az = fmaf(w, (float)h.z, az);
            aw = fmaf(w, (float)h.w, aw);
        }
    }
    v4h hs = *(const v4h*)&Hh[(size_t)n * 96 + c4 * 4];
    float sw = di * di;
    float4 bv = *(const float4*)&b[c4 * 4];
    ax = fmaf(sw, (float)hs.x, ax) + bv.x;
    ay = fmaf(sw, (float)hs.y, ay) + bv.y;
    az = fmaf(sw, (float)hs.z, az) + bv.z;
    aw = fmaf(sw, (float)hs.w, aw) + bv.w;
    if (mode == 0) {
        ax = fmaxf(ax, 0.f); ay = fmaxf(ay, 0.f);
        az = fmaxf(az, 0.f); aw = fmaxf(aw, 0.f);
        v4h o;
        o.x = (_Float16)ax; o.y = (_Float16)ay;
        o.z = (_Float16)az; o.w = (_Float16)aw;
        int off = (n >> 4) * 1536 + (c4 >> 1) * 128 + (n & 15) * 8 + (c4 & 1) * 4;
        *(v4h*)&Fsw[off] = o;
    } else {
        float4 o = {ax, ay, az, aw};
        *(float4*)&out[(size_t)n * 96 + c4 * 4] = o;
    }
}

// ---------------- launch ----------------

extern "C" void kernel_launch(void* const* d_in, const int* in_sizes, int n_in,
                              void* d_out, int out_size, void* d_ws, size_t ws_size,
                              hipStream_t stream) {
    const float* x = (const float*)d_in[0];
    const int* ei = (const int*)d_in[1];
    const float* W1 = (const float*)d_in[2];
    const float* b1 = (const float*)d_in[3];
    const float* W2 = (const float*)d_in[4];
    const float* b2 = (const float*)d_in[5];
    const float* W3 = (const float*)d_in[6];
    const float* b3 = (const float*)d_in[7];
    const float* W4 = (const float*)d_in[8];
    const float* b4 = (const float*)d_in[9];
    float* out = (float*)d_out;

    const int* src = ei;
    const int* dst = ei + NE;

    char* ws = (char*)d_ws;
    size_t o = 0;
    _Float16* Hh = (_Float16*)(ws + o);   o += al256((size_t)NN * 96 * 2);
    _Float16* Fsw = (_Float16*)(ws + o);  o += al256((size_t)NN * 96 * 2);
    _Float16* W1sw = (_Float16*)(ws + o); o += al256((size_t)96 * K1 * 2);
    _Float16* W2sw = (_Float16*)(ws + o); o += al256((size_t)96 * 96 * 2);
    _Float16* W3sw = (_Float16*)(ws + o); o += al256((size_t)96 * 96 * 2);
    _Float16* W4sw = (_Float16*)(ws + o); o += al256((size_t)96 * 96 * 2);
    int* cnt8 = (int*)(ws + o);           o += al256((size_t)NPART * NN * 4);
    int* offs8 = (int*)(ws + o);          o += al256(((size_t)NPART * NN + 1) * 4);
    int* cursor8 = (int*)(ws + o);        o += al256((size_t)NPART * NN * 4);
    float* dinv = (float*)(ws + o);       o += al256((size_t)NN * 4);
    int* es = (int*)(ws + o);             o += al256((size_t)NE * 4);
    int* bsum = (int*)(ws + o);           o += al256(1024 * 4);
    int* boff = (int*)(ws + o);           o += al256(1024 * 4);

    const int M8 = NPART * NN;                     // 400000
    const int NB_EDGE = (NE + 255) / 256;          // 3125
    const int NB_SCANV = (M8 + 1023) / 1024;       // 391
    const int NB_NODE = (NN + 255) / 256;          // 196
    const int NB_GEMM = (NT + 7) / 8;              // 391
    const int NB_AGG = (NN + 7) / 8;               // 6250

    // preprocessing
    hipMemsetAsync(cnt8, 0, (size_t)M8 * 4, stream);
    count_deg_k<<<NB_EDGE, 256, 0, stream>>>(dst, cnt8, NE);
    scan1v_k<<<NB_SCANV, 256, 0, stream>>>(cnt8, offs8, bsum, M8);
    scan2v_k<<<1, 256, 0, stream>>>(bsum, boff, NB_SCANV);
    scan3v_k<<<NB_SCANV, 256, 0, stream>>>(offs8, boff, cursor8, M8);
    dinv_k<<<NB_NODE, 256, 0, stream>>>(cnt8, dinv, offs8);
    scatter_k<<<NB_EDGE, 256, 0, stream>>>(src, dst, cursor8, es, NE);
    wconv_k<<<12, 256, 0, stream>>>(W1, W1sw, K1);
    wconv_k<<<9, 256, 0, stream>>>(W2, W2sw, CH);
    wconv_k<<<9, 256, 0, stream>>>(W3, W3sw, CH);
    wconv_k<<<9, 256, 0, stream>>>(W4, W4sw, CH);

    // layer 1
    gemm_k<K1, true><<<NB_GEMM, 128, 0, stream>>>(x, Fsw, W1sw, Hh);
    agg_k<<<NB_AGG, 192, 0, stream>>>(Hh, offs8, es, dinv, b1, Fsw, out, 0);
    // layer 2
    gemm_k<CH, false><<<NB_GEMM, 128, 0, stream>>>(nullptr, Fsw, W2sw, Hh);
    agg_k<<<NB_AGG, 192, 0, stream>>>(Hh, offs8, es, dinv, b2, Fsw, out, 0);
    // layer 3
    gemm_k<CH, false><<<NB_GEMM, 128, 0, stream>>>(nullptr, Fsw, W3sw, Hh);
    agg_k<<<NB_AGG, 192, 0, stream>>>(Hh, offs8, es, dinv, b3, Fsw, out, 0);
    // layer 4 -> fp32 out, no relu
    gemm_k<CH, false><<<NB_GEMM, 128, 0, stream>>>(nullptr, Fsw, W4sw, Hh);
    agg_k<<<NB_AGG, 192, 0, stream>>>(Hh, offs8, es, dinv, b4, Fsw, out, 1);
}

// Round 4
// 303.748 us; speedup vs baseline: 1.5963x; 1.5963x over previous
//
#include <hip/hip_runtime.h>
#include <hip/hip_fp16.h>

// GCN: 4 layers, N=50000, E=800000, C: 128->96->96->96->96
// - 2-level bucket sort by dst (coarse LDS-histogram binning into 196 buckets,
//   then per-bucket in-LDS counting sort -> coalesced es writes, offs + dinv
//   produced for free). No device-wide random 4B scatter.
// - MFMA f16 GEMM (256 thr, 4 waves), A from swizzled-fp16 global (written by
//   agg), W pre-swizzled fp16, D^T trick for packed row-major fp16 stores.
// - agg: single contiguous edge range per node, 12 lanes x v8h (16B gathers),
//   unroll x4 for MLP; fp32 accumulate; writes swizzled fp16 for next GEMM.

#define NN 50000
#define NE 800000
#define K1 128
#define CH 96
#define NT 3125    // NN/16 row-tiles (exact)
#define NPB 196    // dst buckets of 256 nodes
#define BCAP 5120  // max edges per bucket (mean 4082, sigma ~64)

typedef _Float16 v8h __attribute__((ext_vector_type(8)));
typedef _Float16 v4h __attribute__((ext_vector_type(4)));
typedef float f4 __attribute__((ext_vector_type(4)));

static inline size_t al256(size_t x) { return (x + 255) & ~size_t(255); }

// ---------------- pass 1: bucket histogram ----------------
__global__ __launch_bounds__(256) void hist_k(const int* __restrict__ dst,
                                              int* __restrict__ btotal) {
    __shared__ int h[NPB];
    int tid = threadIdx.x;
    if (tid < NPB) h[tid] = 0;
    __syncthreads();
    int base = blockIdx.x * 1024;
#pragma unroll
    for (int j = 0; j < 4; j++) {
        int i = base + j * 256 + tid;
        if (i < NE) atomicAdd(&h[dst[i] >> 8], 1);
    }
    __syncthreads();
    if (tid < NPB && h[tid]) atomicAdd(&btotal[tid], h[tid]);
}

// ---------------- bucket scan (1 block) ----------------
__global__ __launch_bounds__(256) void bscan_k(const int* __restrict__ btotal,
                                               int* __restrict__ bbase,
                                               int* __restrict__ bcursor) {
    __shared__ int s[256];
    int tid = threadIdx.x;
    int v = (tid < NPB) ? btotal[tid] : 0;
    s[tid] = v;
    __syncthreads();
    for (int d = 1; d < 256; d <<= 1) {
        int t = (tid >= d) ? s[tid - d] : 0;
        __syncthreads();
        s[tid] += t;
        __syncthreads();
    }
    int ex = s[tid] - v;
    if (tid < NPB) {
        bbase[tid] = ex;
        bcursor[tid] = ex;
    }
}

// ---------------- pass 2: bin edges into bucket regions ----------------
__global__ __launch_bounds__(256) void bin_k(const int* __restrict__ src,
                                             const int* __restrict__ dst,
                                             int* __restrict__ bcursor,
                                             int2* __restrict__ est) {
    __shared__ int h2[NPB];
    __shared__ int basel[NPB];
    int tid = threadIdx.x;
    if (tid < NPB) h2[tid] = 0;
    __syncthreads();
    int base = blockIdx.x * 1024;
    int sv[4], dv[4], bk[4], rk[4];
#pragma unroll
    for (int j = 0; j < 4; j++) {
        int i = base + j * 256 + tid;
        bk[j] = -1;
        if (i < NE) {
            sv[j] = src[i];
            dv[j] = dst[i];
            bk[j] = dv[j] >> 8;
            rk[j] = atomicAdd(&h2[bk[j]], 1);
        }
    }
    __syncthreads();
    if (tid < NPB && h2[tid]) basel[tid] = atomicAdd(&bcursor[tid], h2[tid]);
    __syncthreads();
#pragma unroll
    for (int j = 0; j < 4; j++) {
        if (bk[j] >= 0) {
            int pos = basel[bk[j]] + rk[j];
            est[pos] = make_int2(sv[j], dv[j]);
        }
    }
}

// ---------------- pass 3: per-bucket in-LDS sort; emit es, offs, dinv --------
__global__ __launch_bounds__(256) void fine_k(const int2* __restrict__ est,
                                              const int* __restrict__ bbase,
                                              const int* __restrict__ btotal,
                                              int* __restrict__ es,
                                              int* __restrict__ offs,
                                              float* __restrict__ dinv) {
    __shared__ int lsrc[BCAP];
    __shared__ unsigned short ldst[BCAP];
    __shared__ int lout[BCAP];
    __shared__ int hist[256];
    __shared__ int sc[256];
    __shared__ int cur[256];

    int b = blockIdx.x;
    int tid = threadIdx.x;
    int base = bbase[b];
    int cnt = btotal[b];
    if (cnt > BCAP) cnt = BCAP;  // cannot happen at this E/N; guards LDS

    hist[tid] = 0;
    __syncthreads();
    for (int j = tid; j < cnt; j += 256) {
        int2 e = est[base + j];
        lsrc[j] = e.x;
        int l = e.y - (b << 8);
        ldst[j] = (unsigned short)l;
        atomicAdd(&hist[l], 1);
    }
    __syncthreads();
    int hv = hist[tid];
    sc[tid] = hv;
    __syncthreads();
    for (int d = 1; d < 256; d <<= 1) {
        int t = (tid >= d) ? sc[tid - d] : 0;
        __syncthreads();
        sc[tid] += t;
        __syncthreads();
    }
    int excl = sc[tid] - hv;
    int n = (b << 8) + tid;
    if (n < NN) {
        offs[n] = base + excl;
        dinv[n] = rsqrtf(1.0f + (float)hv);
    } else if (n == NN) {
        offs[NN] = base + excl;  // == NE (all edges precede)
    }
    cur[tid] = excl;
    __syncthreads();
    for (int j = tid; j < cnt; j += 256) {
        int r = atomicAdd(&cur[ldst[j]], 1);
        lout[r] = lsrc[j];
    }
    __syncthreads();
    for (int j = tid; j < cnt; j += 256) es[base + j] = lout[j];
}

// ---------------- W[K][96] fp32 -> swizzled fp16 B-operand ----------------
__global__ void wconv_k(const float* __restrict__ W, _Float16* __restrict__ Wsw, int K) {
    int id = blockIdx.x * 256 + threadIdx.x;
    int kc = K / 4;
    int n = id / kc, k4 = id % kc;
    if (n < 96) {
        int k0 = k4 * 4;
        v4h o;
        o.x = (_Float16)W[(k0 + 0) * 96 + n];
        o.y = (_Float16)W[(k0 + 1) * 96 + n];
        o.z = (_Float16)W[(k0 + 2) * 96 + n];
        o.w = (_Float16)W[(k0 + 3) * 96 + n];
        int off = (n >> 4) * (16 * K) + (k0 >> 3) * 128 + (n & 15) * 8 + (k0 & 7);
        *(v4h*)&Wsw[off] = o;
    }
}

// ---------------- MFMA GEMM: Hh[NN x 96](fp16 row-major) = A @ W ----------------
// 256 threads = 4 waves; wave computes 2 row-tiles (32 rows) x 96 cols.
// D^T trick: mfma(b_frag, a_frag, acc) -> lane holds row = l15, 4 consecutive
// cols = quad*4 + reg -> packed 8B row-major stores.
template <int K, bool STAGE>
__global__ __launch_bounds__(256) void gemm_k(const float* __restrict__ Xf,
                                              const _Float16* __restrict__ Asw,
                                              const _Float16* __restrict__ Wsw,
                                              _Float16* __restrict__ Hh) {
    constexpr int KK = K / 32;
    constexpr int LDSN = STAGE ? 128 * K : 8;
    __shared__ _Float16 lds[LDSN];

    int tid = threadIdx.x;
    int wave = tid >> 6;
    int lane = tid & 63;
    int l15 = lane & 15, quad = lane >> 4;
    int bt0 = blockIdx.x * 8;
    int wt0 = bt0 + wave * 2;

    if (STAGE) {
        int row0 = bt0 * 16;
        for (int i = tid; i < 128 * (K / 4); i += 256) {
            int r = i / (K / 4), c = i % (K / 4);
            int gr = row0 + r;
            float4 v = make_float4(0.f, 0.f, 0.f, 0.f);
            if (gr < NN) v = *(const float4*)&Xf[(size_t)gr * K + c * 4];
            int k0 = c * 4;
            v4h h;
            h.x = (_Float16)v.x; h.y = (_Float16)v.y;
            h.z = (_Float16)v.z; h.w = (_Float16)v.w;
            int off = (r >> 4) * (16 * K) + (k0 >> 3) * 128 + (r & 15) * 8 + (k0 & 7);
            *(v4h*)&lds[off] = h;
        }
        __syncthreads();
    }

    f4 acc[2][6];
#pragma unroll
    for (int rt = 0; rt < 2; rt++)
#pragma unroll
        for (int cb = 0; cb < 6; cb++) acc[rt][cb] = {0.f, 0.f, 0.f, 0.f};

    for (int kk = 0; kk < KK; kk++) {
        v8h b[6];
#pragma unroll
        for (int cb = 0; cb < 6; cb++)
            b[cb] = ((const v8h*)Wsw)[cb * (2 * K) + (kk * 4 + quad) * 16 + l15];
        v8h a[2];
#pragma unroll
        for (int rt = 0; rt < 2; rt++) {
            if (STAGE) {
                int off = (wave * 2 + rt) * (16 * K) + (kk * 4 + quad) * 128 + l15 * 8;
                a[rt] = *(v8h*)&lds[off];
            } else {
                int t = wt0 + rt;
                if (t > NT - 1) t = NT - 1;
                a[rt] = ((const v8h*)Asw)[t * 192 + (kk * 4 + quad) * 16 + l15];
            }
        }
#pragma unroll
        for (int rt = 0; rt < 2; rt++)
#pragma unroll
            for (int cb = 0; cb < 6; cb++)
                acc[rt][cb] = __builtin_amdgcn_mfma_f32_16x16x32_f16(b[cb], a[rt], acc[rt][cb], 0, 0, 0);
    }

#pragma unroll
    for (int rt = 0; rt < 2; rt++) {
        int t = wt0 + rt;
        if (t < NT) {
            int row = t * 16 + l15;
#pragma unroll
            for (int cb = 0; cb < 6; cb++) {
                v4h o;
                o.x = (_Float16)acc[rt][cb].x;
                o.y = (_Float16)acc[rt][cb].y;
                o.z = (_Float16)acc[rt][cb].z;
                o.w = (_Float16)acc[rt][cb].w;
                *(v4h*)&Hh[(size_t)row * 96 + cb * 16 + quad * 4] = o;
            }
        }
    }
}

// ---------------- aggregation ----------------
// OUT[n] = sum_{e in [offs[n],offs[n+1])} dinv[src]*dinv[n]*Hh[src]
//          + dinv[n]^2*Hh[n] + b ; 12 lanes/node (v8h chunks), 16 nodes/block.
// mode 0: relu + swizzled fp16 -> Fsw ; mode 1: fp32 row-major -> out
__global__ __launch_bounds__(192) void agg_k(const _Float16* __restrict__ Hh,
                                             const int* __restrict__ offs,
                                             const int* __restrict__ es,
                                             const float* __restrict__ dinv,
                                             const float* __restrict__ b,
                                             _Float16* __restrict__ Fsw,
                                             float* __restrict__ out, int mode) {
    int tid = threadIdx.x;
    int g = tid / 12, c8 = tid % 12;
    int n = blockIdx.x * 16 + g;  // grid 3125 x 16 == NN exactly
    float di = dinv[n];
    int e0 = offs[n], e1 = offs[n + 1];
    float a0 = 0.f, a1 = 0.f, a2 = 0.f, a3 = 0.f, a4 = 0.f, a5 = 0.f, a6 = 0.f, a7 = 0.f;
    int e = e0;
    for (; e + 4 <= e1; e += 4) {
        int s0 = es[e], s1 = es[e + 1], s2 = es[e + 2], s3 = es[e + 3];
        float w0 = dinv[s0] * di, w1 = dinv[s1] * di, w2 = dinv[s2] * di, w3 = dinv[s3] * di;
        v8h h0 = *(const v8h*)&Hh[(size_t)s0 * 96 + c8 * 8];
        v8h h1 = *(const v8h*)&Hh[(size_t)s1 * 96 + c8 * 8];
        v8h h2 = *(const v8h*)&Hh[(size_t)s2 * 96 + c8 * 8];
        v8h h3 = *(const v8h*)&Hh[(size_t)s3 * 96 + c8 * 8];
        a0 = fmaf(w0, (float)h0.s0, a0); a1 = fmaf(w0, (float)h0.s1, a1);
        a2 = fmaf(w0, (float)h0.s2, a2); a3 = fmaf(w0, (float)h0.s3, a3);
        a4 = fmaf(w0, (float)h0.s4, a4); a5 = fmaf(w0, (float)h0.s5, a5);
        a6 = fmaf(w0, (float)h0.s6, a6); a7 = fmaf(w0, (float)h0.s7, a7);
        a0 = fmaf(w1, (float)h1.s0, a0); a1 = fmaf(w1, (float)h1.s1, a1);
        a2 = fmaf(w1, (float)h1.s2, a2); a3 = fmaf(w1, (float)h1.s3, a3);
        a4 = fmaf(w1, (float)h1.s4, a4); a5 = fmaf(w1, (float)h1.s5, a5);
        a6 = fmaf(w1, (float)h1.s6, a6); a7 = fmaf(w1, (float)h1.s7, a7);
        a0 = fmaf(w2, (float)h2.s0, a0); a1 = fmaf(w2, (float)h2.s1, a1);
        a2 = fmaf(w2, (float)h2.s2, a2); a3 = fmaf(w2, (float)h2.s3, a3);
        a4 = fmaf(w2, (float)h2.s4, a4); a5 = fmaf(w2, (float)h2.s5, a5);
        a6 = fmaf(w2, (float)h2.s6, a6); a7 = fmaf(w2, (float)h2.s7, a7);
        a0 = fmaf(w3, (float)h3.s0, a0); a1 = fmaf(w3, (float)h3.s1, a1);
        a2 = fmaf(w3, (float)h3.s2, a2); a3 = fmaf(w3, (float)h3.s3, a3);
        a4 = fmaf(w3, (float)h3.s4, a4); a5 = fmaf(w3, (float)h3.s5, a5);
        a6 = fmaf(w3, (float)h3.s6, a6); a7 = fmaf(w3, (float)h3.s7, a7);
    }
    for (; e < e1; e++) {
        int s0 = es[e];
        float w0 = dinv[s0] * di;
        v8h h0 = *(const v8h*)&Hh[(size_t)s0 * 96 + c8 * 8];
        a0 = fmaf(w0, (float)h0.s0, a0); a1 = fmaf(w0, (float)h0.s1, a1);
        a2 = fmaf(w0, (float)h0.s2, a2); a3 = fmaf(w0, (float)h0.s3, a3);
        a4 = fmaf(w0, (float)h0.s4, a4); a5 = fmaf(w0, (float)h0.s5, a5);
        a6 = fmaf(w0, (float)h0.s6, a6); a7 = fmaf(w0, (float)h0.s7, a7);
    }
    // self-loop + bias
    {
        float sw = di * di;
        v8h hs = *(const v8h*)&Hh[(size_t)n * 96 + c8 * 8];
        float4 bv0 = *(const float4*)&b[c8 * 8];
        float4 bv1 = *(const float4*)&b[c8 * 8 + 4];
        a0 = fmaf(sw, (float)hs.s0, a0) + bv0.x;
        a1 = fmaf(sw, (float)hs.s1, a1) + bv0.y;
        a2 = fmaf(sw, (float)hs.s2, a2) + bv0.z;
        a3 = fmaf(sw, (float)hs.s3, a3) + bv0.w;
        a4 = fmaf(sw, (float)hs.s4, a4) + bv1.x;
        a5 = fmaf(sw, (float)hs.s5, a5) + bv1.y;
        a6 = fmaf(sw, (float)hs.s6, a6) + bv1.z;
        a7 = fmaf(sw, (float)hs.s7, a7) + bv1.w;
    }
    if (mode == 0) {
        a0 = fmaxf(a0, 0.f); a1 = fmaxf(a1, 0.f); a2 = fmaxf(a2, 0.f); a3 = fmaxf(a3, 0.f);
        a4 = fmaxf(a4, 0.f); a5 = fmaxf(a5, 0.f); a6 = fmaxf(a6, 0.f); a7 = fmaxf(a7, 0.f);
        v8h o;
        o.s0 = (_Float16)a0; o.s1 = (_Float16)a1; o.s2 = (_Float16)a2; o.s3 = (_Float16)a3;
        o.s4 = (_Float16)a4; o.s5 = (_Float16)a5; o.s6 = (_Float16)a6; o.s7 = (_Float16)a7;
        // swizzled A-operand store: element offset (n>>4)*1536 + c8*128 + (n&15)*8
        int off = (n >> 4) * 1536 + c8 * 128 + (n & 15) * 8;
        *(v8h*)&Fsw[off] = o;
    } else {
        float4 o0 = {a0, a1, a2, a3};
        float4 o1 = {a4, a5, a6, a7};
        *(float4*)&out[(size_t)n * 96 + c8 * 8] = o0;
        *(float4*)&out[(size_t)n * 96 + c8 * 8 + 4] = o1;
    }
}

// ---------------- launch ----------------

extern "C" void kernel_launch(void* const* d_in, const int* in_sizes, int n_in,
                              void* d_out, int out_size, void* d_ws, size_t ws_size,
                              hipStream_t stream) {
    const float* x = (const float*)d_in[0];
    const int* ei = (const int*)d_in[1];
    const float* W1 = (const float*)d_in[2];
    const float* b1 = (const float*)d_in[3];
    const float* W2 = (const float*)d_in[4];
    const float* b2 = (const float*)d_in[5];
    const float* W3 = (const float*)d_in[6];
    const float* b3 = (const float*)d_in[7];
    const float* W4 = (const float*)d_in[8];
    const float* b4 = (const float*)d_in[9];
    float* out = (float*)d_out;

    const int* src = ei;
    const int* dst = ei + NE;

    char* ws = (char*)d_ws;
    size_t o = 0;
    _Float16* Hh = (_Float16*)(ws + o);   o += al256((size_t)NN * 96 * 2);
    _Float16* Fsw = (_Float16*)(ws + o);  o += al256((size_t)NN * 96 * 2);
    _Float16* W1sw = (_Float16*)(ws + o); o += al256((size_t)96 * K1 * 2);
    _Float16* W2sw = (_Float16*)(ws + o); o += al256((size_t)96 * 96 * 2);
    _Float16* W3sw = (_Float16*)(ws + o); o += al256((size_t)96 * 96 * 2);
    _Float16* W4sw = (_Float16*)(ws + o); o += al256((size_t)96 * 96 * 2);
    int2* est = (int2*)(ws + o);          o += al256((size_t)NE * 8);
    int* es = (int*)(ws + o);             o += al256((size_t)NE * 4);
    int* offs = (int*)(ws + o);           o += al256((size_t)(NN + 1) * 4);
    float* dinv = (float*)(ws + o);       o += al256((size_t)NN * 4);
    int* btotal = (int*)(ws + o);         o += al256((size_t)NPB * 4);
    int* bbase = (int*)(ws + o);          o += al256((size_t)(NPB + 1) * 4);
    int* bcursor = (int*)(ws + o);        o += al256((size_t)NPB * 4);

    const int NB_EDGE4 = (NE + 1023) / 1024;  // 782
    const int NB_GEMM = (NT + 7) / 8;         // 391
    const int NB_AGG = NN / 16;               // 3125 exact

    // preprocessing: 2-level bucket sort by dst
    hipMemsetAsync(btotal, 0, (size_t)NPB * 4, stream);
    hist_k<<<NB_EDGE4, 256, 0, stream>>>(dst, btotal);
    bscan_k<<<1, 256, 0, stream>>>(btotal, bbase, bcursor);
    bin_k<<<NB_EDGE4, 256, 0, stream>>>(src, dst, bcursor, est);
    fine_k<<<NPB, 256, 0, stream>>>(est, bbase, btotal, es, offs, dinv);
    wconv_k<<<12, 256, 0, stream>>>(W1, W1sw, K1);
    wconv_k<<<9, 256, 0, stream>>>(W2, W2sw, CH);
    wconv_k<<<9, 256, 0, stream>>>(W3, W3sw, CH);
    wconv_k<<<9, 256, 0, stream>>>(W4, W4sw, CH);

    // layer 1
    gemm_k<K1, true><<<NB_GEMM, 256, 0, stream>>>(x, Fsw, W1sw, Hh);
    agg_k<<<NB_AGG, 192, 0, stream>>>(Hh, offs, es, dinv, b1, Fsw, out, 0);
    // layer 2
    gemm_k<CH, false><<<NB_GEMM, 256, 0, stream>>>(nullptr, Fsw, W2sw, Hh);
    agg_k<<<NB_AGG, 192, 0, stream>>>(Hh, offs, es, dinv, b2, Fsw, out, 0);
    // layer 3
    gemm_k<CH, false><<<NB_GEMM, 256, 0, stream>>>(nullptr, Fsw, W3sw, Hh);
    agg_k<<<NB_AGG, 192, 0, stream>>>(Hh, offs, es, dinv, b3, Fsw, out, 0);
    // layer 4 -> fp32 out, no relu
    gemm_k<CH, false><<<NB_GEMM, 256, 0, stream>>>(nullptr, Fsw, W4sw, Hh);
    agg_k<<<NB_AGG, 192, 0, stream>>>(Hh, offs, es, dinv, b4, Fsw, out, 1);
}

// Round 5
// 288.966 us; speedup vs baseline: 1.6779x; 1.0512x over previous
//
#include <hip/hip_runtime.h>
#include <hip/hip_fp16.h>

// GCN: 4 layers, N=50000, E=800000, C: 128->96->96->96->96
// - bucket sort by dst: bin_k reserves per-bucket slab space directly (no
//   histogram pre-pass), fine_k sorts each bucket in LDS, computes the global
//   bucket prefix itself, and emits ushort es + offs + dinv.
// - MFMA f16 GEMM: 1 row-tile per wave (grid 2x), A-fragments preloaded before
//   the K-loop, W pre-swizzled fp16 (L1-resident), D^T trick for packed
//   row-major fp16 stores.
// - agg: contiguous edge range per node, 12 lanes x v8h (16B gathers),
//   unroll x8; fp32 accumulate; writes swizzled fp16 for the next GEMM.

#define NN 50000
#define NE 800000
#define K1 128
#define CH 96
#define NT 3125    // NN/16 row-tiles (exact)
#define NPB 196    // dst buckets of 256 nodes
#define BCAP 5120  // slab capacity per bucket (mean 4082, ~16 sigma headroom)

typedef _Float16 v8h __attribute__((ext_vector_type(8)));
typedef _Float16 v4h __attribute__((ext_vector_type(4)));
typedef float f4 __attribute__((ext_vector_type(4)));
typedef unsigned short ushort_t;

static inline size_t al256(size_t x) { return (x + 255) & ~size_t(255); }

// ---------------- fused: weight swizzle + bcnt zero ----------------
// W[K][96] fp32 row-major -> swizzled fp16 B-operand layout.
// id < 3072: W1 (K=128); next 3*2304: W2/W3/W4 (K=96).
__global__ __launch_bounds__(256) void wconv_k(const float* __restrict__ W1f,
                                               const float* __restrict__ W2f,
                                               const float* __restrict__ W3f,
                                               const float* __restrict__ W4f,
                                               _Float16* __restrict__ W1sw,
                                               _Float16* __restrict__ W2sw,
                                               _Float16* __restrict__ W3sw,
                                               _Float16* __restrict__ W4sw,
                                               int* __restrict__ bcnt) {
    int id = blockIdx.x * 256 + threadIdx.x;
    if (id < NPB) bcnt[id] = 0;
    const float* W;
    _Float16* Wsw;
    int K, lid;
    if (id < 3072) {            // 96*32
        W = W1f; Wsw = W1sw; K = K1; lid = id;
    } else {
        int r = id - 3072;
        if (r >= 3 * 2304) return;
        int wsel = r / 2304;
        lid = r % 2304;         // 96*24
        K = CH;
        W = (wsel == 0) ? W2f : (wsel == 1) ? W3f : W4f;
        Wsw = (wsel == 0) ? W2sw : (wsel == 1) ? W3sw : W4sw;
    }
    int kc = K / 4;
    int n = lid / kc, k0 = (lid % kc) * 4;
    v4h o;
    o.x = (_Float16)W[(k0 + 0) * 96 + n];
    o.y = (_Float16)W[(k0 + 1) * 96 + n];
    o.z = (_Float16)W[(k0 + 2) * 96 + n];
    o.w = (_Float16)W[(k0 + 3) * 96 + n];
    int off = (n >> 4) * (16 * K) + (k0 >> 3) * 128 + (n & 15) * 8 + (k0 & 7);
    *(v4h*)&Wsw[off] = o;
}

// ---------------- pass 1: bin edges into per-bucket slabs ----------------
// packed word: src (16 bits) | local-dst (8 bits) << 16
__global__ __launch_bounds__(256) void bin_k(const int* __restrict__ src,
                                             const int* __restrict__ dst,
                                             int* __restrict__ bcnt,
                                             int* __restrict__ est) {
    __shared__ int h2[NPB];
    __shared__ int basel[NPB];
    int tid = threadIdx.x;
    if (tid < NPB) h2[tid] = 0;
    __syncthreads();
    int base = blockIdx.x * 1024;
    int wv[4], bk[4], rk[4];
#pragma unroll
    for (int j = 0; j < 4; j++) {
        int i = base + j * 256 + tid;
        bk[j] = -1;
        if (i < NE) {
            int s = src[i], d = dst[i];
            bk[j] = d >> 8;
            rk[j] = atomicAdd(&h2[bk[j]], 1);
            wv[j] = s | ((d & 255) << 16);
        }
    }
    __syncthreads();
    if (tid < NPB && h2[tid]) basel[tid] = atomicAdd(&bcnt[tid], h2[tid]);
    __syncthreads();
#pragma unroll
    for (int j = 0; j < 4; j++) {
        if (bk[j] >= 0) est[bk[j] * BCAP + basel[bk[j]] + rk[j]] = wv[j];
    }
}

// ---------------- pass 2: per-bucket in-LDS sort; emit es/offs/dinv ----------
__global__ __launch_bounds__(256) void fine_k(const int* __restrict__ est,
                                              const int* __restrict__ bcnt,
                                              ushort_t* __restrict__ es,
                                              int* __restrict__ offs,
                                              float* __restrict__ dinv) {
    __shared__ ushort_t lsrc[BCAP];
    __shared__ unsigned char ldst[BCAP];
    __shared__ ushort_t lout[BCAP];
    __shared__ int sc[256];
    __shared__ int hist[256];
    __shared__ int cur[256];

    int b = blockIdx.x;
    int tid = threadIdx.x;

    // global bucket prefix: scan bcnt[0..NPB)
    int bc = (tid < NPB) ? bcnt[tid] : 0;
    sc[tid] = bc;
    __syncthreads();
    for (int d = 1; d < 256; d <<= 1) {
        int t = (tid >= d) ? sc[tid - d] : 0;
        __syncthreads();
        sc[tid] += t;
        __syncthreads();
    }
    int cnt = bcnt[b];
    if (cnt > BCAP) cnt = BCAP;
    int base = sc[b] - cnt;  // exclusive prefix for this bucket

    hist[tid] = 0;
    __syncthreads();
    for (int j = tid; j < cnt; j += 256) {
        int w = est[b * BCAP + j];
        lsrc[j] = (ushort_t)(w & 0xFFFF);
        int l = (w >> 16) & 255;
        ldst[j] = (unsigned char)l;
        atomicAdd(&hist[l], 1);
    }
    __syncthreads();
    int hv = hist[tid];
    sc[tid] = hv;
    __syncthreads();
    for (int d = 1; d < 256; d <<= 1) {
        int t = (tid >= d) ? sc[tid - d] : 0;
        __syncthreads();
        sc[tid] += t;
        __syncthreads();
    }
    int excl = sc[tid] - hv;
    int n = (b << 8) + tid;
    if (n < NN) {
        offs[n] = base + excl;
        dinv[n] = rsqrtf(1.0f + (float)hv);
    } else if (n == NN) {
        offs[NN] = base + excl;  // == NE
    }
    cur[tid] = excl;
    __syncthreads();
    for (int j = tid; j < cnt; j += 256) {
        int r = atomicAdd(&cur[ldst[j]], 1);
        lout[r] = lsrc[j];
    }
    __syncthreads();
    for (int j = tid; j < cnt; j += 256) es[base + j] = lout[j];
}

// ---------------- MFMA GEMM: Hh[NN x 96](fp16 row-major) = A @ W ----------------
// 256 threads = 4 waves; 1 row-tile (16 rows x 96 cols) per wave.
// A-fragments for all K-steps preloaded before the MFMA loop.
// D^T trick: mfma(b_frag, a_frag, acc) -> lane holds row = l15, 4 consecutive
// cols = quad*4 + reg -> packed 8B row-major stores.
template <int K, bool STAGE>
__global__ __launch_bounds__(256) void gemm_k(const float* __restrict__ Xf,
                                              const _Float16* __restrict__ Asw,
                                              const _Float16* __restrict__ Wsw,
                                              _Float16* __restrict__ Hh) {
    constexpr int KK = K / 32;
    constexpr int LDSN = STAGE ? 64 * K : 8;
    __shared__ _Float16 lds[LDSN];

    int tid = threadIdx.x;
    int wave = tid >> 6;
    int lane = tid & 63;
    int l15 = lane & 15, quad = lane >> 4;
    int t = blockIdx.x * 4 + wave;
    int tt = (t > NT - 1) ? NT - 1 : t;

    if (STAGE) {
        int row0 = blockIdx.x * 64;
        for (int i = tid; i < 64 * (K / 4); i += 256) {
            int r = i / (K / 4), c = i % (K / 4);
            int gr = row0 + r;
            float4 v = make_float4(0.f, 0.f, 0.f, 0.f);
            if (gr < NN) v = *(const float4*)&Xf[(size_t)gr * K + c * 4];
            int k0 = c * 4;
            v4h h;
            h.x = (_Float16)v.x; h.y = (_Float16)v.y;
            h.z = (_Float16)v.z; h.w = (_Float16)v.w;
            int off = (r >> 4) * (16 * K) + (k0 >> 3) * 128 + (r & 15) * 8 + (k0 & 7);
            *(v4h*)&lds[off] = h;
        }
        __syncthreads();
    }

    // preload all A-fragments (3-4 x 16B: all in flight before first MFMA)
    v8h a[KK];
#pragma unroll
    for (int kk = 0; kk < KK; kk++) {
        if (STAGE) {
            int off = wave * (16 * K) + (kk * 4 + quad) * 128 + l15 * 8;
            a[kk] = *(v8h*)&lds[off];
        } else {
            a[kk] = ((const v8h*)Asw)[tt * (2 * K) + (kk * 4 + quad) * 16 + l15];
        }
    }

    f4 acc[6];
#pragma unroll
    for (int cb = 0; cb < 6; cb++) acc[cb] = {0.f, 0.f, 0.f, 0.f};

#pragma unroll
    for (int kk = 0; kk < KK; kk++) {
        v8h b[6];
#pragma unroll
        for (int cb = 0; cb < 6; cb++)
            b[cb] = ((const v8h*)Wsw)[cb * (2 * K) + (kk * 4 + quad) * 16 + l15];
#pragma unroll
        for (int cb = 0; cb < 6; cb++)
            acc[cb] = __builtin_amdgcn_mfma_f32_16x16x32_f16(b[cb], a[kk], acc[cb], 0, 0, 0);
    }

    if (t < NT) {
        int row = t * 16 + l15;
#pragma unroll
        for (int cb = 0; cb < 6; cb++) {
            v4h o;
            o.x = (_Float16)acc[cb].x;
            o.y = (_Float16)acc[cb].y;
            o.z = (_Float16)acc[cb].z;
            o.w = (_Float16)acc[cb].w;
            *(v4h*)&Hh[(size_t)row * 96 + cb * 16 + quad * 4] = o;
        }
    }
}

// ---------------- aggregation ----------------
// OUT[n] = sum_{e in [offs[n],offs[n+1])} dinv[src]*dinv[n]*Hh[src]
//          + dinv[n]^2*Hh[n] + b ; 12 lanes/node (v8h), 16 nodes/block,
//          unroll x8 (8 gathers in flight per lane).
// mode 0: relu + swizzled fp16 -> Fsw ; mode 1: fp32 row-major -> out
__device__ __forceinline__ void acc8(v8h h, float w, float* a) {
    a[0] = fmaf(w, (float)h.s0, a[0]);
    a[1] = fmaf(w, (float)h.s1, a[1]);
    a[2] = fmaf(w, (float)h.s2, a[2]);
    a[3] = fmaf(w, (float)h.s3, a[3]);
    a[4] = fmaf(w, (float)h.s4, a[4]);
    a[5] = fmaf(w, (float)h.s5, a[5]);
    a[6] = fmaf(w, (float)h.s6, a[6]);
    a[7] = fmaf(w, (float)h.s7, a[7]);
}

__global__ __launch_bounds__(192) void agg_k(const _Float16* __restrict__ Hh,
                                             const int* __restrict__ offs,
                                             const ushort_t* __restrict__ es,
                                             const float* __restrict__ dinv,
                                             const float* __restrict__ b,
                                             _Float16* __restrict__ Fsw,
                                             float* __restrict__ out, int mode) {
    int tid = threadIdx.x;
    int g = tid / 12, c8 = tid % 12;
    int n = blockIdx.x * 16 + g;  // grid 3125 x 16 == NN exactly
    float di = dinv[n];
    int e0 = offs[n], e1 = offs[n + 1];
    float a[8] = {0.f, 0.f, 0.f, 0.f, 0.f, 0.f, 0.f, 0.f};
    int e = e0;
    for (; e + 8 <= e1; e += 8) {
        int s[8];
        float w[8];
#pragma unroll
        for (int j = 0; j < 8; j++) s[j] = es[e + j];
#pragma unroll
        for (int j = 0; j < 8; j++) w[j] = dinv[s[j]] * di;
        v8h h[8];
#pragma unroll
        for (int j = 0; j < 8; j++) h[j] = *(const v8h*)&Hh[(size_t)s[j] * 96 + c8 * 8];
#pragma unroll
        for (int j = 0; j < 8; j++) acc8(h[j], w[j], a);
    }
    for (; e < e1; e++) {
        int s0 = es[e];
        float w0 = dinv[s0] * di;
        v8h h0 = *(const v8h*)&Hh[(size_t)s0 * 96 + c8 * 8];
        acc8(h0, w0, a);
    }
    // self-loop + bias
    {
        v8h hs = *(const v8h*)&Hh[(size_t)n * 96 + c8 * 8];
        acc8(hs, di * di, a);
        float4 bv0 = *(const float4*)&b[c8 * 8];
        float4 bv1 = *(const float4*)&b[c8 * 8 + 4];
        a[0] += bv0.x; a[1] += bv0.y; a[2] += bv0.z; a[3] += bv0.w;
        a[4] += bv1.x; a[5] += bv1.y; a[6] += bv1.z; a[7] += bv1.w;
    }
    if (mode == 0) {
#pragma unroll
        for (int j = 0; j < 8; j++) a[j] = fmaxf(a[j], 0.f);
        v8h o;
        o.s0 = (_Float16)a[0]; o.s1 = (_Float16)a[1];
        o.s2 = (_Float16)a[2]; o.s3 = (_Float16)a[3];
        o.s4 = (_Float16)a[4]; o.s5 = (_Float16)a[5];
        o.s6 = (_Float16)a[6]; o.s7 = (_Float16)a[7];
        int off = (n >> 4) * 1536 + c8 * 128 + (n & 15) * 8;
        *(v8h*)&Fsw[off] = o;
    } else {
        float4 o0 = {a[0], a[1], a[2], a[3]};
        float4 o1 = {a[4], a[5], a[6], a[7]};
        *(float4*)&out[(size_t)n * 96 + c8 * 8] = o0;
        *(float4*)&out[(size_t)n * 96 + c8 * 8 + 4] = o1;
    }
}

// ---------------- launch ----------------

extern "C" void kernel_launch(void* const* d_in, const int* in_sizes, int n_in,
                              void* d_out, int out_size, void* d_ws, size_t ws_size,
                              hipStream_t stream) {
    const float* x = (const float*)d_in[0];
    const int* ei = (const int*)d_in[1];
    const float* W1 = (const float*)d_in[2];
    const float* b1 = (const float*)d_in[3];
    const float* W2 = (const float*)d_in[4];
    const float* b2 = (const float*)d_in[5];
    const float* W3 = (const float*)d_in[6];
    const float* b3 = (const float*)d_in[7];
    const float* W4 = (const float*)d_in[8];
    const float* b4 = (const float*)d_in[9];
    float* out = (float*)d_out;

    const int* src = ei;
    const int* dst = ei + NE;

    char* ws = (char*)d_ws;
    size_t o = 0;
    _Float16* Hh = (_Float16*)(ws + o);   o += al256((size_t)NN * 96 * 2);
    _Float16* Fsw = (_Float16*)(ws + o);  o += al256((size_t)NN * 96 * 2);
    _Float16* W1sw = (_Float16*)(ws + o); o += al256((size_t)96 * K1 * 2);
    _Float16* W2sw = (_Float16*)(ws + o); o += al256((size_t)96 * 96 * 2);
    _Float16* W3sw = (_Float16*)(ws + o); o += al256((size_t)96 * 96 * 2);
    _Float16* W4sw = (_Float16*)(ws + o); o += al256((size_t)96 * 96 * 2);
    int* est = (int*)(ws + o);            o += al256((size_t)NPB * BCAP * 4);
    ushort_t* es = (ushort_t*)(ws + o);   o += al256((size_t)NE * 2);
    int* offs = (int*)(ws + o);           o += al256((size_t)(NN + 1) * 4);
    float* dinv = (float*)(ws + o);       o += al256((size_t)NN * 4);
    int* bcnt = (int*)(ws + o);           o += al256((size_t)NPB * 4);

    const int NB_EDGE4 = (NE + 1023) / 1024;  // 782
    const int NB_GEMM = (NT + 3) / 4;         // 782
    const int NB_AGG = NN / 16;               // 3125 exact

    // preprocessing
    wconv_k<<<39, 256, 0, stream>>>(W1, W2, W3, W4, W1sw, W2sw, W3sw, W4sw, bcnt);
    bin_k<<<NB_EDGE4, 256, 0, stream>>>(src, dst, bcnt, est);
    fine_k<<<NPB, 256, 0, stream>>>(est, bcnt, es, offs, dinv);

    // layer 1
    gemm_k<K1, true><<<NB_GEMM, 256, 0, stream>>>(x, Fsw, W1sw, Hh);
    agg_k<<<NB_AGG, 192, 0, stream>>>(Hh, offs, es, dinv, b1, Fsw, out, 0);
    // layer 2
    gemm_k<CH, false><<<NB_GEMM, 256, 0, stream>>>(nullptr, Fsw, W2sw, Hh);
    agg_k<<<NB_AGG, 192, 0, stream>>>(Hh, offs, es, dinv, b2, Fsw, out, 0);
    // layer 3
    gemm_k<CH, false><<<NB_GEMM, 256, 0, stream>>>(nullptr, Fsw, W3sw, Hh);
    agg_k<<<NB_AGG, 192, 0, stream>>>(Hh, offs, es, dinv, b3, Fsw, out, 0);
    // layer 4 -> fp32 out, no relu
    gemm_k<CH, false><<<NB_GEMM, 256, 0, stream>>>(nullptr, Fsw, W4sw, Hh);
    agg_k<<<NB_AGG, 192, 0, stream>>>(Hh, offs, es, dinv, b4, Fsw, out, 1);
}

// Round 6
// 280.135 us; speedup vs baseline: 1.7308x; 1.0315x over previous
//
#include <hip/hip_runtime.h>
#include <hip/hip_fp16.h>

// GCN: 4 layers, N=50000, E=800000, C: 128->96->96->96->96
// - bucket sort by dst (bin_k slabs + fine_k in-LDS sort) -> es(ushort), offs,
//   dinv, and nodeord (per-bucket degree-sorted node order -> degree-uniform
//   waves in the gather loops).
// - gemm1: MFMA f16, X fp32 staged to LDS, D^T trick -> row-major fp16 H.
// - fused_k (x3): gather-aggregate 16 nodes (+bias, relu) -> 3KB LDS A-tile ->
//   MFMA with next layer's swizzled W -> row-major fp16 H. No intermediate.
// - aggf_k: final gather-aggregate + b4 -> fp32 out.

#define NN 50000
#define NE 800000
#define K1 128
#define CH 96
#define NT 3125    // NN/16 row-tiles (exact)
#define NPB 196    // dst buckets of 256 nodes
#define BCAP 5120  // slab capacity per bucket (mean 4082, ~16 sigma headroom)
#define NSLOT (NPB * 256)  // 50176 nodeord slots

typedef _Float16 v8h __attribute__((ext_vector_type(8)));
typedef _Float16 v4h __attribute__((ext_vector_type(4)));
typedef float f4 __attribute__((ext_vector_type(4)));
typedef unsigned short ushort_t;

static inline size_t al256(size_t x) { return (x + 255) & ~size_t(255); }

// ---------------- fused: weight swizzle + bcnt zero ----------------
__global__ __launch_bounds__(256) void wconv_k(const float* __restrict__ W1f,
                                               const float* __restrict__ W2f,
                                               const float* __restrict__ W3f,
                                               const float* __restrict__ W4f,
                                               _Float16* __restrict__ W1sw,
                                               _Float16* __restrict__ W2sw,
                                               _Float16* __restrict__ W3sw,
                                               _Float16* __restrict__ W4sw,
                                               int* __restrict__ bcnt) {
    int id = blockIdx.x * 256 + threadIdx.x;
    if (id < NPB) bcnt[id] = 0;
    const float* W;
    _Float16* Wsw;
    int K, lid;
    if (id < 3072) {            // 96*32
        W = W1f; Wsw = W1sw; K = K1; lid = id;
    } else {
        int r = id - 3072;
        if (r >= 3 * 2304) return;
        int wsel = r / 2304;
        lid = r % 2304;         // 96*24
        K = CH;
        W = (wsel == 0) ? W2f : (wsel == 1) ? W3f : W4f;
        Wsw = (wsel == 0) ? W2sw : (wsel == 1) ? W3sw : W4sw;
    }
    int kc = K / 4;
    int n = lid / kc, k0 = (lid % kc) * 4;
    v4h o;
    o.x = (_Float16)W[(k0 + 0) * 96 + n];
    o.y = (_Float16)W[(k0 + 1) * 96 + n];
    o.z = (_Float16)W[(k0 + 2) * 96 + n];
    o.w = (_Float16)W[(k0 + 3) * 96 + n];
    int off = (n >> 4) * (16 * K) + (k0 >> 3) * 128 + (n & 15) * 8 + (k0 & 7);
    *(v4h*)&Wsw[off] = o;
}

// ---------------- pass 1: bin edges into per-bucket slabs ----------------
// packed word: src (16 bits) | local-dst (8 bits) << 16
__global__ __launch_bounds__(256) void bin_k(const int* __restrict__ src,
                                             const int* __restrict__ dst,
                                             int* __restrict__ bcnt,
                                             int* __restrict__ est) {
    __shared__ int h2[NPB];
    __shared__ int basel[NPB];
    int tid = threadIdx.x;
    if (tid < NPB) h2[tid] = 0;
    __syncthreads();
    int base = blockIdx.x * 1024;
    int wv[4], bk[4], rk[4];
#pragma unroll
    for (int j = 0; j < 4; j++) {
        int i = base + j * 256 + tid;
        bk[j] = -1;
        if (i < NE) {
            int s = src[i], d = dst[i];
            bk[j] = d >> 8;
            rk[j] = atomicAdd(&h2[bk[j]], 1);
            wv[j] = s | ((d & 255) << 16);
        }
    }
    __syncthreads();
    if (tid < NPB && h2[tid]) basel[tid] = atomicAdd(&bcnt[tid], h2[tid]);
    __syncthreads();
#pragma unroll
    for (int j = 0; j < 4; j++) {
        if (bk[j] >= 0) est[bk[j] * BCAP + basel[bk[j]] + rk[j]] = wv[j];
    }
}

// ---------------- pass 2: per-bucket sort; emit es/offs/dinv/nodeord ---------
__global__ __launch_bounds__(256) void fine_k(const int* __restrict__ est,
                                              const int* __restrict__ bcnt,
                                              ushort_t* __restrict__ es,
                                              int* __restrict__ offs,
                                              float* __restrict__ dinv,
                                              int* __restrict__ nodeord) {
    __shared__ ushort_t lsrc[BCAP];
    __shared__ unsigned char ldst[BCAP];
    __shared__ ushort_t lout[BCAP];
    __shared__ int sc[256];
    __shared__ int hist[256];
    __shared__ int cur[256];
    __shared__ int dh[256];

    int b = blockIdx.x;
    int tid = threadIdx.x;

    // global bucket prefix: scan bcnt[0..NPB)
    int bc = (tid < NPB) ? bcnt[tid] : 0;
    sc[tid] = bc;
    __syncthreads();
    for (int d = 1; d < 256; d <<= 1) {
        int t = (tid >= d) ? sc[tid - d] : 0;
        __syncthreads();
        sc[tid] += t;
        __syncthreads();
    }
    int cnt = bcnt[b];
    if (cnt > BCAP) cnt = BCAP;
    int base = sc[b] - cnt;  // exclusive prefix for this bucket

    hist[tid] = 0;
    __syncthreads();
    for (int j = tid; j < cnt; j += 256) {
        int w = est[b * BCAP + j];
        lsrc[j] = (ushort_t)(w & 0xFFFF);
        int l = (w >> 16) & 255;
        ldst[j] = (unsigned char)l;
        atomicAdd(&hist[l], 1);
    }
    __syncthreads();
    int hv = hist[tid];
    sc[tid] = hv;
    __syncthreads();
    for (int d = 1; d < 256; d <<= 1) {
        int t = (tid >= d) ? sc[tid - d] : 0;
        __syncthreads();
        sc[tid] += t;
        __syncthreads();
    }
    int excl = sc[tid] - hv;
    int n = (b << 8) + tid;
    int nvalid = NN - (b << 8);
    if (nvalid > 256) nvalid = 256;
    bool valid = tid < nvalid;
    if (valid) {
        offs[n] = base + excl;
        dinv[n] = rsqrtf(1.0f + (float)hv);
    }
    if (n == NN) offs[NN] = base + excl;  // == NE (last bucket)
    cur[tid] = excl;
    dh[tid] = 0;
    __syncthreads();
    for (int j = tid; j < cnt; j += 256) {
        int r = atomicAdd(&cur[ldst[j]], 1);
        lout[r] = lsrc[j];
    }
    int dv = (hv > 255) ? 255 : hv;
    if (valid) atomicAdd(&dh[dv], 1);
    __syncthreads();
    for (int j = tid; j < cnt; j += 256) es[base + j] = lout[j];
    // degree-rank counting sort -> nodeord
    int dhv = dh[tid];
    sc[tid] = dhv;
    __syncthreads();
    for (int d = 1; d < 256; d <<= 1) {
        int t = (tid >= d) ? sc[tid - d] : 0;
        __syncthreads();
        sc[tid] += t;
        __syncthreads();
    }
    cur[tid] = sc[tid] - dhv;
    __syncthreads();
    if (valid) {
        int slot = atomicAdd(&cur[dv], 1);
        nodeord[b * 256 + slot] = n;      // slots [0, nvalid)
    } else {
        nodeord[b * 256 + tid] = b << 8;  // invalid slots: safe duplicate
    }
}

// ---------------- gemm1: H[NN x 96](fp16 row-major) = fp16(X) @ W1 ----------
// 256 threads = 4 waves; 1 row-tile (16 rows) per wave; X staged to LDS.
template <int K>
__global__ __launch_bounds__(256) void gemm_k(const float* __restrict__ Xf,
                                              const _Float16* __restrict__ Wsw,
                                              _Float16* __restrict__ Hh) {
    constexpr int KK = K / 32;
    __shared__ _Float16 lds[64 * K];

    int tid = threadIdx.x;
    int wave = tid >> 6;
    int lane = tid & 63;
    int l15 = lane & 15, quad = lane >> 4;
    int t = blockIdx.x * 4 + wave;

    int row0 = blockIdx.x * 64;
    for (int i = tid; i < 64 * (K / 4); i += 256) {
        int r = i / (K / 4), c = i % (K / 4);
        int gr = row0 + r;
        float4 v = make_float4(0.f, 0.f, 0.f, 0.f);
        if (gr < NN) v = *(const float4*)&Xf[(size_t)gr * K + c * 4];
        int k0 = c * 4;
        v4h h;
        h.x = (_Float16)v.x; h.y = (_Float16)v.y;
        h.z = (_Float16)v.z; h.w = (_Float16)v.w;
        int off = (r >> 4) * (16 * K) + (k0 >> 3) * 128 + (r & 15) * 8 + (k0 & 7);
        *(v4h*)&lds[off] = h;
    }
    __syncthreads();

    v8h a[KK];
#pragma unroll
    for (int kk = 0; kk < KK; kk++) {
        int off = wave * (16 * K) + (kk * 4 + quad) * 128 + l15 * 8;
        a[kk] = *(v8h*)&lds[off];
    }

    f4 acc[6];
#pragma unroll
    for (int cb = 0; cb < 6; cb++) acc[cb] = {0.f, 0.f, 0.f, 0.f};

#pragma unroll
    for (int kk = 0; kk < KK; kk++) {
        v8h b[6];
#pragma unroll
        for (int cb = 0; cb < 6; cb++)
            b[cb] = ((const v8h*)Wsw)[cb * (2 * K) + (kk * 4 + quad) * 16 + l15];
#pragma unroll
        for (int cb = 0; cb < 6; cb++)
            acc[cb] = __builtin_amdgcn_mfma_f32_16x16x32_f16(b[cb], a[kk], acc[cb], 0, 0, 0);
    }

    if (t < NT) {
        int row = t * 16 + l15;
#pragma unroll
        for (int cb = 0; cb < 6; cb++) {
            v4h o;
            o.x = (_Float16)acc[cb].x;
            o.y = (_Float16)acc[cb].y;
            o.z = (_Float16)acc[cb].z;
            o.w = (_Float16)acc[cb].w;
            *(v4h*)&Hh[(size_t)row * 96 + cb * 16 + quad * 4] = o;
        }
    }
}

// ---------------- shared gather-accumulate helper ----------------
__device__ __forceinline__ void acc8(v8h h, float w, float* a) {
    a[0] = fmaf(w, (float)h.s0, a[0]);
    a[1] = fmaf(w, (float)h.s1, a[1]);
    a[2] = fmaf(w, (float)h.s2, a[2]);
    a[3] = fmaf(w, (float)h.s3, a[3]);
    a[4] = fmaf(w, (float)h.s4, a[4]);
    a[5] = fmaf(w, (float)h.s5, a[5]);
    a[6] = fmaf(w, (float)h.s6, a[6]);
    a[7] = fmaf(w, (float)h.s7, a[7]);
}

__device__ __forceinline__ void gather_node(const _Float16* __restrict__ Hh,
                                            const int* __restrict__ offs,
                                            const ushort_t* __restrict__ es,
                                            const float* __restrict__ dinv,
                                            const float* __restrict__ bias,
                                            int n, int c8, float* a) {
    float di = dinv[n];
    int e0 = offs[n], e1 = offs[n + 1];
    int e = e0;
    for (; e + 8 <= e1; e += 8) {
        int s[8];
        float w[8];
#pragma unroll
        for (int j = 0; j < 8; j++) s[j] = es[e + j];
#pragma unroll
        for (int j = 0; j < 8; j++) w[j] = dinv[s[j]] * di;
        v8h h[8];
#pragma unroll
        for (int j = 0; j < 8; j++) h[j] = *(const v8h*)&Hh[(size_t)s[j] * 96 + c8 * 8];
#pragma unroll
        for (int j = 0; j < 8; j++) acc8(h[j], w[j], a);
    }
    for (; e < e1; e++) {
        int s0 = es[e];
        float w0 = dinv[s0] * di;
        v8h h0 = *(const v8h*)&Hh[(size_t)s0 * 96 + c8 * 8];
        acc8(h0, w0, a);
    }
    // self-loop + bias
    v8h hs = *(const v8h*)&Hh[(size_t)n * 96 + c8 * 8];
    acc8(hs, di * di, a);
    float4 bv0 = *(const float4*)&bias[c8 * 8];
    float4 bv1 = *(const float4*)&bias[c8 * 8 + 4];
    a[0] += bv0.x; a[1] += bv0.y; a[2] += bv0.z; a[3] += bv0.w;
    a[4] += bv1.x; a[5] += bv1.y; a[6] += bv1.z; a[7] += bv1.w;
}

// ---------------- fused: F = relu(agg(Hprev)+bias); Hnext = F @ W ------------
// block 192 = 16 nodes x 12 lanes (gather) then 3 waves x 2 col-blocks (MFMA).
__global__ __launch_bounds__(192) void fused_k(const _Float16* __restrict__ Hprev,
                                               const int* __restrict__ offs,
                                               const ushort_t* __restrict__ es,
                                               const float* __restrict__ dinv,
                                               const float* __restrict__ bias,
                                               const _Float16* __restrict__ Wsw,
                                               const int* __restrict__ nodeord,
                                               _Float16* __restrict__ Hnext) {
    __shared__ _Float16 atile[1536];  // 16 x 96 in MFMA-A swizzle
    int tid = threadIdx.x;
    int g = tid / 12, c8 = tid % 12;
    int n = nodeord[blockIdx.x * 16 + g];
    float a[8] = {0.f, 0.f, 0.f, 0.f, 0.f, 0.f, 0.f, 0.f};
    gather_node(Hprev, offs, es, dinv, bias, n, c8, a);
    v8h o;
    o.s0 = (_Float16)fmaxf(a[0], 0.f); o.s1 = (_Float16)fmaxf(a[1], 0.f);
    o.s2 = (_Float16)fmaxf(a[2], 0.f); o.s3 = (_Float16)fmaxf(a[3], 0.f);
    o.s4 = (_Float16)fmaxf(a[4], 0.f); o.s5 = (_Float16)fmaxf(a[5], 0.f);
    o.s6 = (_Float16)fmaxf(a[6], 0.f); o.s7 = (_Float16)fmaxf(a[7], 0.f);
    *(v8h*)&atile[c8 * 128 + g * 8] = o;
    __syncthreads();

    // MFMA phase: wave w handles col-blocks {2w, 2w+1}
    int wave = tid >> 6;
    int lane = tid & 63;
    int l15 = lane & 15, quad = lane >> 4;
    v8h af[3];
#pragma unroll
    for (int kk = 0; kk < 3; kk++)
        af[kk] = *(v8h*)&atile[(kk * 4 + quad) * 128 + l15 * 8];
    int nrow = nodeord[blockIdx.x * 16 + l15];
#pragma unroll
    for (int c = 0; c < 2; c++) {
        int cb = wave * 2 + c;
        f4 acc = {0.f, 0.f, 0.f, 0.f};
#pragma unroll
        for (int kk = 0; kk < 3; kk++) {
            v8h bf = ((const v8h*)Wsw)[cb * 192 + (kk * 4 + quad) * 16 + l15];
            acc = __builtin_amdgcn_mfma_f32_16x16x32_f16(bf, af[kk], acc, 0, 0, 0);
        }
        v4h o2;
        o2.x = (_Float16)acc.x; o2.y = (_Float16)acc.y;
        o2.z = (_Float16)acc.z; o2.w = (_Float16)acc.w;
        *(v4h*)&Hnext[(size_t)nrow * 96 + cb * 16 + quad * 4] = o2;
    }
}

// ---------------- final aggregation -> fp32 out ----------------
__global__ __launch_bounds__(192) void aggf_k(const _Float16* __restrict__ Hh,
                                              const int* __restrict__ offs,
                                              const ushort_t* __restrict__ es,
                                              const float* __restrict__ dinv,
                                              const float* __restrict__ bias,
                                              const int* __restrict__ nodeord,
                                              float* __restrict__ out) {
    int tid = threadIdx.x;
    int g = tid / 12, c8 = tid % 12;
    int n = nodeord[blockIdx.x * 16 + g];
    float a[8] = {0.f, 0.f, 0.f, 0.f, 0.f, 0.f, 0.f, 0.f};
    gather_node(Hh, offs, es, dinv, bias, n, c8, a);
    float4 o0 = {a[0], a[1], a[2], a[3]};
    float4 o1 = {a[4], a[5], a[6], a[7]};
    *(float4*)&out[(size_t)n * 96 + c8 * 8] = o0;
    *(float4*)&out[(size_t)n * 96 + c8 * 8 + 4] = o1;
}

// ---------------- launch ----------------

extern "C" void kernel_launch(void* const* d_in, const int* in_sizes, int n_in,
                              void* d_out, int out_size, void* d_ws, size_t ws_size,
                              hipStream_t stream) {
    const float* x = (const float*)d_in[0];
    const int* ei = (const int*)d_in[1];
    const float* W1 = (const float*)d_in[2];
    const float* b1 = (const float*)d_in[3];
    const float* W2 = (const float*)d_in[4];
    const float* b2 = (const float*)d_in[5];
    const float* W3 = (const float*)d_in[6];
    const float* b3 = (const float*)d_in[7];
    const float* W4 = (const float*)d_in[8];
    const float* b4 = (const float*)d_in[9];
    float* out = (float*)d_out;

    const int* src = ei;
    const int* dst = ei + NE;

    char* ws = (char*)d_ws;
    size_t o = 0;
    _Float16* Ha = (_Float16*)(ws + o);   o += al256((size_t)NN * 96 * 2);
    _Float16* Hb = (_Float16*)(ws + o);   o += al256((size_t)NN * 96 * 2);
    _Float16* W1sw = (_Float16*)(ws + o); o += al256((size_t)96 * K1 * 2);
    _Float16* W2sw = (_Float16*)(ws + o); o += al256((size_t)96 * 96 * 2);
    _Float16* W3sw = (_Float16*)(ws + o); o += al256((size_t)96 * 96 * 2);
    _Float16* W4sw = (_Float16*)(ws + o); o += al256((size_t)96 * 96 * 2);
    int* est = (int*)(ws + o);            o += al256((size_t)NPB * BCAP * 4);
    ushort_t* es = (ushort_t*)(ws + o);   o += al256((size_t)NE * 2);
    int* offs = (int*)(ws + o);           o += al256((size_t)(NN + 1) * 4);
    float* dinv = (float*)(ws + o);       o += al256((size_t)NN * 4);
    int* bcnt = (int*)(ws + o);           o += al256((size_t)NPB * 4);
    int* nodeord = (int*)(ws + o);        o += al256((size_t)NSLOT * 4);

    const int NB_EDGE4 = (NE + 1023) / 1024;  // 782
    const int NB_GEMM = (NT + 3) / 4;         // 782
    const int NB_AGG = NSLOT / 16;            // 3136

    // preprocessing
    wconv_k<<<39, 256, 0, stream>>>(W1, W2, W3, W4, W1sw, W2sw, W3sw, W4sw, bcnt);
    bin_k<<<NB_EDGE4, 256, 0, stream>>>(src, dst, bcnt, est);
    fine_k<<<NPB, 256, 0, stream>>>(est, bcnt, es, offs, dinv, nodeord);

    // layer 1 GEMM: Ha = fp16(x @ W1)
    gemm_k<K1><<<NB_GEMM, 256, 0, stream>>>(x, W1sw, Ha);
    // fused layers: agg + bias + relu + next GEMM
    fused_k<<<NB_AGG, 192, 0, stream>>>(Ha, offs, es, dinv, b1, W2sw, nodeord, Hb);
    fused_k<<<NB_AGG, 192, 0, stream>>>(Hb, offs, es, dinv, b2, W3sw, nodeord, Ha);
    fused_k<<<NB_AGG, 192, 0, stream>>>(Ha, offs, es, dinv, b3, W4sw, nodeord, Hb);
    // final aggregation -> fp32 out
    aggf_k<<<NB_AGG, 192, 0, stream>>>(Hb, offs, es, dinv, b4, nodeord, out);
}